// Round 7
// baseline (251.262 us; speedup 1.0000x reference)
//
#include <hip/hip_runtime.h>
#include <hip/hip_fp16.h>
#include <stdint.h>

#define I_DIM 2048
#define O_DIM 2048
#define B_DIM 4096
#define KOUT 16

// ---- DIAGNOSTIC REP FACTORS (divide visible dur by these; remove next round) ----
#define REP_CM 16
#define REP_QT 6
#define REP_GM 4

typedef int i32x4 __attribute__((ext_vector_type(4)));
typedef float f32x4 __attribute__((ext_vector_type(4)));
typedef _Float16 f16x8 __attribute__((ext_vector_type(8)));

#define TO_LDS(p) ((__attribute__((address_space(3))) void*)(p))
#define TO_GLB(p) ((const __attribute__((address_space(1))) void*)(p))

// ---------------- Stage 1: column absmax partials (no atomics, no memset) ----------------
// grid (8,16): block (x,y) writes cm2[y][x*256+t] = max over rows y*128..y*128+127.
__global__ void colmax_kernel(const float* __restrict__ W, float* __restrict__ cm2) {
  const int j = blockIdx.x * 256 + threadIdx.x;
  const int y = blockIdx.y;
  for (int rep = 0; rep < REP_CM; ++rep) {          // DIAGNOSTIC repeat
    float m = 0.0f;
    const float* p = W + (size_t)(y * 128) * I_DIM + j;
#pragma unroll 8
    for (int i = 0; i < 128; ++i)
      m = fmaxf(m, fabsf(p[(size_t)i * I_DIM]));
    cm2[y * I_DIM + j] = m;
    asm volatile("" ::: "memory");                  // force real re-execution
  }
}

// ---------------- Stage 2: partial-reduce + per-block topk + quantize 12 rows ----------------
__global__ __launch_bounds__(256) void quant_topk_kernel(
    const float* __restrict__ X, const float* __restrict__ W,
    const float* __restrict__ cm2,
    signed char* __restrict__ xq, signed char* __restrict__ wq,
    float* __restrict__ xmax, float* __restrict__ wmax,
    _Float16* __restrict__ xunqh,   // [B][32] halves (k padded 16->32 w/ zeros)
    _Float16* __restrict__ wunqh) { // [O][32] halves
  __shared__ float keepL[I_DIM];    // 8 KB
  __shared__ int idxL[KOUT];
  __shared__ float wm_[4];
  __shared__ int wi_[4];
  __shared__ int sel;

  const int t = threadIdx.x;

  // ---- reduce 16 partial rows -> per-thread 8 column maxima (exact: fmaxf assoc on nonneg) ----
  float4 a = {0.0f, 0.0f, 0.0f, 0.0f}, b = a;
#pragma unroll
  for (int y = 0; y < 16; ++y) {
    const float4* c4 = (const float4*)(cm2 + (size_t)y * I_DIM);
    float4 pa = c4[t * 2], pb = c4[t * 2 + 1];
    a.x = fmaxf(a.x, pa.x); a.y = fmaxf(a.y, pa.y);
    a.z = fmaxf(a.z, pa.z); a.w = fmaxf(a.w, pa.w);
    b.x = fmaxf(b.x, pb.x); b.y = fmaxf(b.y, pb.y);
    b.z = fmaxf(b.z, pb.z); b.w = fmaxf(b.w, pb.w);
  }
  float v[8] = {a.x, a.y, a.z, a.w, b.x, b.y, b.z, b.w};
  {
    float4 one = {1.0f, 1.0f, 1.0f, 1.0f};
    ((float4*)keepL)[t] = one;
    ((float4*)keepL)[t + 256] = one;
  }
  // ---- local top-16 (identical tie-breaks as verified kernels) ----
  for (int k = 0; k < KOUT; ++k) {
    float m = v[0]; int mi = 0;
#pragma unroll
    for (int r = 1; r < 8; ++r) if (v[r] > m) { m = v[r]; mi = r; }
    int gi = t * 8 + mi;
#pragma unroll
    for (int s = 32; s; s >>= 1) {
      float om = __shfl_down(m, s);
      int oi = __shfl_down(gi, s);
      if (om > m) { m = om; gi = oi; }
    }
    if ((t & 63) == 0) { wm_[t >> 6] = m; wi_[t >> 6] = gi; }
    __syncthreads();
    if (t == 0) {
      float bm = wm_[0]; int bi = wi_[0];
      for (int w2 = 1; w2 < 4; ++w2) if (wm_[w2] > bm) { bm = wm_[w2]; bi = wi_[w2]; }
      idxL[k] = bi; keepL[bi] = 0.0f; sel = bi;
    }
    __syncthreads();
    if (t == (sel >> 3)) v[sel & 7] = -1.0f;
  }
  __syncthreads();   // keepL / idxL fully visible to all waves

  // ---- quantize: one row per wave, 3 rounds (12 rows / 4 waves) ----
  const int wave = t >> 6;
  const int lane = t & 63;
  for (int rep = 0; rep < REP_QT; ++rep) {          // DIAGNOSTIC repeat
    for (int rr = wave; rr < 12; rr += 4) {
      const int u = blockIdx.x * 12 + rr;           // 0..6143
      const bool isW = u < O_DIM;
      const int r = isW ? u : (u - O_DIM);
      const float* src = isW ? (W + (size_t)r * I_DIM) : (X + (size_t)r * I_DIM);
      const float4* s4 = (const float4*)src;
      const float4* k4 = (const float4*)keepL;

      float4 d[8];
      float mx = 0.0f;
#pragma unroll
      for (int i = 0; i < 8; ++i) {                 // coalesced: float4 index i*64+lane
        float4 dv = s4[i * 64 + lane];
        float4 kk = k4[i * 64 + lane];
        dv.x *= kk.x; dv.y *= kk.y; dv.z *= kk.z; dv.w *= kk.w;
        d[i] = dv;
        mx = fmaxf(mx, fmaxf(fmaxf(fabsf(dv.x), fabsf(dv.y)),
                             fmaxf(fabsf(dv.z), fabsf(dv.w))));
      }
#pragma unroll
      for (int s = 32; s; s >>= 1) mx = fmaxf(mx, __shfl_xor(mx, s));
      const float sc = 127.0f / mx;                 // match ref: scale first, mul, trunc
      unsigned* qout = (unsigned*)(isW ? (wq + (size_t)r * I_DIM) : (xq + (size_t)r * I_DIM));
#pragma unroll
      for (int i = 0; i < 8; ++i) {
        unsigned p = (unsigned char)(signed char)(int)(d[i].x * sc)
                   | ((unsigned)(unsigned char)(signed char)(int)(d[i].y * sc) << 8)
                   | ((unsigned)(unsigned char)(signed char)(int)(d[i].z * sc) << 16)
                   | ((unsigned)(unsigned char)(signed char)(int)(d[i].w * sc) << 24);
        qout[i * 64 + lane] = p;
      }
      if (lane == 0) { if (isW) wmax[r] = mx; else xmax[r] = mx; }
      if (lane < KOUT) {
        float ov = src[idxL[lane]];
        _Float16* u16 = isW ? (wunqh + (size_t)r * 32) : (xunqh + (size_t)r * 32);
        u16[lane] = (_Float16)ov;
        u16[lane + KOUT] = (_Float16)0.0f;          // zero-pad k 16..31
      }
    }
    asm volatile("" ::: "memory");                  // force real re-execution
  }
}

// ---------------- Stage 3: int8 GEMM + fused MFMA epilogue (round-5 structure) ----------------
// DIAGNOSTIC: K-loop run REP_GM times, acc summed (identical passes -> sum = REP*v,
// exact integer /REP recovers v; compiler cannot elide any pass).
__global__ __launch_bounds__(256, 2) void gemm_kernel(
    const signed char* __restrict__ Aq,   // M x K (x_q)
    const signed char* __restrict__ Bq,   // N x K (w_q)
    const float* __restrict__ xmaxg,      // M
    const float* __restrict__ wmaxg,      // N
    const _Float16* __restrict__ xunqh,   // M x 32
    const _Float16* __restrict__ wunqh,   // N x 32
    const float* __restrict__ biasg,      // N
    float* __restrict__ out) {            // M x N
  constexpr int N = O_DIM, K = I_DIM;
  __shared__ __align__(16) signed char smem[2][32768];  // per buf: As 16K | Bs 16K

  const int tid = threadIdx.x;
  const int lane = tid & 63;
  const int wave = tid >> 6;
  const int wm = (wave & 1) * 64;
  const int wn = (wave >> 1) * 64;

  // XCD swizzle: 64 tiles per XCD, 8x8 regions
  const int lid = blockIdx.y * gridDim.x + blockIdx.x;   // 0..511
  const int xcd = lid & 7;
  const int pos = lid >> 3;                              // 0..63
  const int by = (xcd >> 1) * 8 + (pos >> 3);            // 0..31 (M tiles)
  const int bx = (xcd & 1) * 8 + (pos & 7);              // 0..15 (N tiles)
  const int m0 = by * 128;
  const int n0 = bx * 128;

  const int srow = tid >> 3;              // 0..31
  const int cslot = tid & 7;              // 0..7
  const int fm = lane & 15;
  const int q = lane >> 4;

  i32x4 acc[4][4] = {};

  // chunk swizzle: LDS slot (r, c) holds global 16B-chunk (c - (r>>1)) & 7
  auto stage = [&](int buf, int kt) {
    signed char* As = &smem[buf][0];
    signed char* Bs = &smem[buf][16384];
#pragma unroll
    for (int a = 0; a < 4; ++a) {
      const int row = a * 32 + srow;
      const int gch = (cslot - (row >> 1)) & 7;
      const signed char* ga = Aq + (size_t)(m0 + row) * K + kt + gch * 16;
      const signed char* gb = Bq + (size_t)(n0 + row) * K + kt + gch * 16;
      __builtin_amdgcn_global_load_lds(TO_GLB(ga), TO_LDS(As + a * 4096 + tid * 16), 16, 0, 0);
      __builtin_amdgcn_global_load_lds(TO_GLB(gb), TO_LDS(Bs + a * 4096 + tid * 16), 16, 0, 0);
    }
  };

  for (int rep = 0; rep < REP_GM; ++rep) {          // DIAGNOSTIC repeat (acc sums)
    stage(0, 0);
    __syncthreads();
#pragma unroll 2
    for (int t = 0; t < K / 128; ++t) {             // 16 iterations
      const int cur = t & 1;
      if (t < K / 128 - 1) stage(cur ^ 1, (t + 1) * 128);   // prefetch first
      const signed char* As = &smem[cur][0];
      const signed char* Bs = &smem[cur][16384];
#pragma unroll
      for (int s = 0; s < 2; ++s) {
        i32x4 af[4], bf[4];
        const int q8 = s * 4 + q;
#pragma unroll
        for (int i = 0; i < 4; ++i) {
          const int ra = wm + i * 16 + fm;
          af[i] = *(const i32x4*)(As + ra * 128 + (((q8 + (ra >> 1)) & 7) << 4));
          const int rb = wn + i * 16 + fm;
          bf[i] = *(const i32x4*)(Bs + rb * 128 + (((q8 + (rb >> 1)) & 7) << 4));
        }
#pragma unroll
        for (int i = 0; i < 4; ++i)
#pragma unroll
          for (int j = 0; j < 4; ++j)
            acc[i][j] = __builtin_amdgcn_mfma_i32_16x16x64_i8(af[i], bf[j], acc[i][j], 0, 0, 0);
      }
      __syncthreads();
    }
    asm volatile("" ::: "memory");                  // force real re-execution
  }

  // ---- epilogue: dequant + fp16 round-trip + rank-16 outlier MFMA + bias ----
  f16x8 afh[4], bfh[4];
#pragma unroll
  for (int i = 0; i < 4; ++i)
    afh[i] = *(const f16x8*)(xunqh + (size_t)(m0 + wm + i * 16 + fm) * 32 + q * 8);
#pragma unroll
  for (int j = 0; j < 4; ++j)
    bfh[j] = *(const f16x8*)(wunqh + (size_t)(n0 + wn + j * 16 + fm) * 32 + q * 8);

#pragma unroll
  for (int i = 0; i < 4; ++i) {
    f32x4 xmv = *(const f32x4*)(xmaxg + m0 + wm + i * 16 + q * 4);
#pragma unroll
    for (int j = 0; j < 4; ++j) {
      int cl = n0 + wn + j * 16 + fm;
      float wmv = wmaxg[cl];
      float bv = biasg[cl];
      f32x4 c;
#pragma unroll
      for (int r = 0; r < 4; ++r) {
        int vi = acc[i][j][r] / REP_GM;             // exact: REP identical passes summed
        float v = (float)vi / 16129.0f;             // IEEE div, matches ref
        v = __half2float(__float2half(v));          // fp16 round-trip (RN)
        c[r] = v * (xmv[r] * wmv) + bv;
      }
      c = __builtin_amdgcn_mfma_f32_16x16x32_f16(afh[i], bfh[j], c, 0, 0, 0);
#pragma unroll
      for (int r = 0; r < 4; ++r)
        out[(size_t)(m0 + wm + i * 16 + q * 4 + r) * N + cl] = c[r];
    }
  }
}

extern "C" void kernel_launch(void* const* d_in, const int* in_sizes, int n_in,
                              void* d_out, int out_size, void* d_ws, size_t ws_size,
                              hipStream_t stream) {
  const float* x    = (const float*)d_in[0];   // 4096 x 2048
  const float* w    = (const float*)d_in[1];   // 2048 x 2048
  const float* bias = (const float*)d_in[2];   // 2048
  float* out = (float*)d_out;
  char* ws = (char*)d_ws;

  float* cm2       = (float*)(ws + 0);             // 16 x 2048 partials = 128 KB
  float* w_max     = (float*)(ws + 131072);        // 8 KB
  float* x_max     = (float*)(ws + 139264);        // 16 KB
  _Float16* x_unqh = (_Float16*)(ws + 155648);     // 256 KB
  _Float16* w_unqh = (_Float16*)(ws + 417792);     // 128 KB
  signed char* w_q = (signed char*)(ws + 548864);     // 4 MB
  signed char* x_q = (signed char*)(ws + 4743168);    // 8 MB (total ~12.5 MB)

  // no memset needed: cm2 fully written by colmax before quant reads it
  colmax_kernel<<<dim3(8, 16), 256, 0, stream>>>(w, cm2);
  quant_topk_kernel<<<512, 256, 0, stream>>>(x, w, cm2, x_q, w_q,
                                             x_max, w_max, x_unqh, w_unqh);
  gemm_kernel<<<dim3(O_DIM / 128, B_DIM / 128), 256, 0, stream>>>(
      x_q, w_q, x_max, w_max, x_unqh, w_unqh, bias, out);
}

// Round 8
// 152.591 us; speedup vs baseline: 1.6466x; 1.6466x over previous
//
#include <hip/hip_runtime.h>
#include <hip/hip_fp16.h>
#include <stdint.h>

#define I_DIM 2048
#define O_DIM 2048
#define B_DIM 4096
#define KOUT 16

typedef int i32x4 __attribute__((ext_vector_type(4)));
typedef float f32x4 __attribute__((ext_vector_type(4)));
typedef _Float16 f16x8 __attribute__((ext_vector_type(8)));

#define TO_LDS(p) ((__attribute__((address_space(3))) void*)(p))
#define TO_GLB(p) ((const __attribute__((address_space(1))) void*)(p))

// ---------------- Stage 1: column absmax partials (no atomics, no memset) ----------------
// grid (8,16): block (x,y) writes cm2[y][x*256+t] = max over rows y*128..y*128+127.
__global__ void colmax_kernel(const float* __restrict__ W, float* __restrict__ cm2) {
  const int j = blockIdx.x * 256 + threadIdx.x;
  const int y = blockIdx.y;
  float m = 0.0f;
  const float* p = W + (size_t)(y * 128) * I_DIM + j;
#pragma unroll 8
  for (int i = 0; i < 128; ++i)
    m = fmaxf(m, fabsf(p[(size_t)i * I_DIM]));
  cm2[y * I_DIM + j] = m;
}

// ---------------- Stage 2: partial-reduce + per-block topk + quantize 12 rows ----------------
__global__ __launch_bounds__(256) void quant_topk_kernel(
    const float* __restrict__ X, const float* __restrict__ W,
    const float* __restrict__ cm2,
    signed char* __restrict__ xq, signed char* __restrict__ wq,
    float* __restrict__ xmax, float* __restrict__ wmax,
    _Float16* __restrict__ xunqh,   // [B][32] halves (k padded 16->32 w/ zeros)
    _Float16* __restrict__ wunqh) { // [O][32] halves
  __shared__ float keepL[I_DIM];    // 8 KB
  __shared__ int idxL[KOUT];
  __shared__ float wm_[4];
  __shared__ int wi_[4];
  __shared__ int sel;

  const int t = threadIdx.x;

  // ---- reduce 16 partial rows -> per-thread 8 column maxima (exact: fmaxf assoc on nonneg) ----
  float4 a = {0.0f, 0.0f, 0.0f, 0.0f}, b = a;
#pragma unroll
  for (int y = 0; y < 16; ++y) {
    const float4* c4 = (const float4*)(cm2 + (size_t)y * I_DIM);
    float4 pa = c4[t * 2], pb = c4[t * 2 + 1];
    a.x = fmaxf(a.x, pa.x); a.y = fmaxf(a.y, pa.y);
    a.z = fmaxf(a.z, pa.z); a.w = fmaxf(a.w, pa.w);
    b.x = fmaxf(b.x, pb.x); b.y = fmaxf(b.y, pb.y);
    b.z = fmaxf(b.z, pb.z); b.w = fmaxf(b.w, pb.w);
  }
  float v[8] = {a.x, a.y, a.z, a.w, b.x, b.y, b.z, b.w};
  {
    float4 one = {1.0f, 1.0f, 1.0f, 1.0f};
    ((float4*)keepL)[t] = one;
    ((float4*)keepL)[t + 256] = one;
  }
  // ---- local top-16 (identical tie-breaks as verified kernels) ----
  for (int k = 0; k < KOUT; ++k) {
    float m = v[0]; int mi = 0;
#pragma unroll
    for (int r = 1; r < 8; ++r) if (v[r] > m) { m = v[r]; mi = r; }
    int gi = t * 8 + mi;
#pragma unroll
    for (int s = 32; s; s >>= 1) {
      float om = __shfl_down(m, s);
      int oi = __shfl_down(gi, s);
      if (om > m) { m = om; gi = oi; }
    }
    if ((t & 63) == 0) { wm_[t >> 6] = m; wi_[t >> 6] = gi; }
    __syncthreads();
    if (t == 0) {
      float bm = wm_[0]; int bi = wi_[0];
      for (int w2 = 1; w2 < 4; ++w2) if (wm_[w2] > bm) { bm = wm_[w2]; bi = wi_[w2]; }
      idxL[k] = bi; keepL[bi] = 0.0f; sel = bi;
    }
    __syncthreads();
    if (t == (sel >> 3)) v[sel & 7] = -1.0f;
  }
  __syncthreads();   // keepL / idxL fully visible to all waves

  // ---- quantize: one row per wave, 3 rounds (12 rows / 4 waves) ----
  const int wave = t >> 6;
  const int lane = t & 63;
  for (int rr = wave; rr < 12; rr += 4) {
    const int u = blockIdx.x * 12 + rr;           // 0..6143
    const bool isW = u < O_DIM;
    const int r = isW ? u : (u - O_DIM);
    const float* src = isW ? (W + (size_t)r * I_DIM) : (X + (size_t)r * I_DIM);
    const float4* s4 = (const float4*)src;
    const float4* k4 = (const float4*)keepL;

    float4 d[8];
    float mx = 0.0f;
#pragma unroll
    for (int i = 0; i < 8; ++i) {                 // coalesced: float4 index i*64+lane
      float4 dv = s4[i * 64 + lane];
      float4 kk = k4[i * 64 + lane];
      dv.x *= kk.x; dv.y *= kk.y; dv.z *= kk.z; dv.w *= kk.w;
      d[i] = dv;
      mx = fmaxf(mx, fmaxf(fmaxf(fabsf(dv.x), fabsf(dv.y)),
                           fmaxf(fabsf(dv.z), fabsf(dv.w))));
    }
#pragma unroll
    for (int s = 32; s; s >>= 1) mx = fmaxf(mx, __shfl_xor(mx, s));
    const float sc = 127.0f / mx;                 // match ref: scale first, mul, trunc
    unsigned* qout = (unsigned*)(isW ? (wq + (size_t)r * I_DIM) : (xq + (size_t)r * I_DIM));
#pragma unroll
    for (int i = 0; i < 8; ++i) {
      unsigned p = (unsigned char)(signed char)(int)(d[i].x * sc)
                 | ((unsigned)(unsigned char)(signed char)(int)(d[i].y * sc) << 8)
                 | ((unsigned)(unsigned char)(signed char)(int)(d[i].z * sc) << 16)
                 | ((unsigned)(unsigned char)(signed char)(int)(d[i].w * sc) << 24);
      qout[i * 64 + lane] = p;
    }
    if (lane == 0) { if (isW) wmax[r] = mx; else xmax[r] = mx; }
    if (lane < KOUT) {
      float ov = src[idxL[lane]];
      _Float16* u16 = isW ? (wunqh + (size_t)r * 32) : (xunqh + (size_t)r * 32);
      u16[lane] = (_Float16)ov;
      u16[lane + KOUT] = (_Float16)0.0f;          // zero-pad k 16..31
    }
  }
}

// ---------------- Stage 3: int8 GEMM (C = Xq * Wq^T) + fused MFMA epilogue ----------------
// Round-5 verified structure: BK=128, double-buffered LDS, prefetch-before-compute,
// one __syncthreads per chunk, XCD-aware block swizzle.
__global__ __launch_bounds__(256, 2) void gemm_kernel(
    const signed char* __restrict__ Aq,   // M x K (x_q)
    const signed char* __restrict__ Bq,   // N x K (w_q)
    const float* __restrict__ xmaxg,      // M
    const float* __restrict__ wmaxg,      // N
    const _Float16* __restrict__ xunqh,   // M x 32
    const _Float16* __restrict__ wunqh,   // N x 32
    const float* __restrict__ biasg,      // N
    float* __restrict__ out) {            // M x N
  constexpr int N = O_DIM, K = I_DIM;
  __shared__ __align__(16) signed char smem[2][32768];  // per buf: As 16K | Bs 16K

  const int tid = threadIdx.x;
  const int lane = tid & 63;
  const int wave = tid >> 6;
  const int wm = (wave & 1) * 64;
  const int wn = (wave >> 1) * 64;

  // XCD swizzle: 64 tiles per XCD, 8x8 regions
  const int lid = blockIdx.y * gridDim.x + blockIdx.x;   // 0..511
  const int xcd = lid & 7;
  const int pos = lid >> 3;                              // 0..63
  const int by = (xcd >> 1) * 8 + (pos >> 3);            // 0..31 (M tiles)
  const int bx = (xcd & 1) * 8 + (pos & 7);              // 0..15 (N tiles)
  const int m0 = by * 128;
  const int n0 = bx * 128;

  const int srow = tid >> 3;              // 0..31
  const int cslot = tid & 7;              // 0..7
  const int fm = lane & 15;
  const int q = lane >> 4;

  i32x4 acc[4][4] = {};

  // chunk swizzle: LDS slot (r, c) holds global 16B-chunk (c - (r>>1)) & 7
  auto stage = [&](int buf, int kt) {
    signed char* As = &smem[buf][0];
    signed char* Bs = &smem[buf][16384];
#pragma unroll
    for (int a = 0; a < 4; ++a) {
      const int row = a * 32 + srow;
      const int gch = (cslot - (row >> 1)) & 7;
      const signed char* ga = Aq + (size_t)(m0 + row) * K + kt + gch * 16;
      const signed char* gb = Bq + (size_t)(n0 + row) * K + kt + gch * 16;
      __builtin_amdgcn_global_load_lds(TO_GLB(ga), TO_LDS(As + a * 4096 + tid * 16), 16, 0, 0);
      __builtin_amdgcn_global_load_lds(TO_GLB(gb), TO_LDS(Bs + a * 4096 + tid * 16), 16, 0, 0);
    }
  };

  stage(0, 0);
  __syncthreads();
#pragma unroll 2
  for (int t = 0; t < K / 128; ++t) {             // 16 iterations
    const int cur = t & 1;
    if (t < K / 128 - 1) stage(cur ^ 1, (t + 1) * 128);   // prefetch first
    const signed char* As = &smem[cur][0];
    const signed char* Bs = &smem[cur][16384];
#pragma unroll
    for (int s = 0; s < 2; ++s) {
      i32x4 af[4], bf[4];
      const int q8 = s * 4 + q;
#pragma unroll
      for (int i = 0; i < 4; ++i) {
        const int ra = wm + i * 16 + fm;
        af[i] = *(const i32x4*)(As + ra * 128 + (((q8 + (ra >> 1)) & 7) << 4));
        const int rb = wn + i * 16 + fm;
        bf[i] = *(const i32x4*)(Bs + rb * 128 + (((q8 + (rb >> 1)) & 7) << 4));
      }
#pragma unroll
      for (int i = 0; i < 4; ++i)
#pragma unroll
        for (int j = 0; j < 4; ++j)
          acc[i][j] = __builtin_amdgcn_mfma_i32_16x16x64_i8(af[i], bf[j], acc[i][j], 0, 0, 0);
    }
    __syncthreads();
  }

  // ---- epilogue: dequant + fp16 round-trip + rank-16 outlier MFMA + bias ----
  f16x8 afh[4], bfh[4];
#pragma unroll
  for (int i = 0; i < 4; ++i)
    afh[i] = *(const f16x8*)(xunqh + (size_t)(m0 + wm + i * 16 + fm) * 32 + q * 8);
#pragma unroll
  for (int j = 0; j < 4; ++j)
    bfh[j] = *(const f16x8*)(wunqh + (size_t)(n0 + wn + j * 16 + fm) * 32 + q * 8);

#pragma unroll
  for (int i = 0; i < 4; ++i) {
    f32x4 xmv = *(const f32x4*)(xmaxg + m0 + wm + i * 16 + q * 4);
#pragma unroll
    for (int j = 0; j < 4; ++j) {
      int cl = n0 + wn + j * 16 + fm;
      float wmv = wmaxg[cl];
      float bv = biasg[cl];
      f32x4 c;
#pragma unroll
      for (int r = 0; r < 4; ++r) {
        float v = (float)acc[i][j][r] / 16129.0f;   // IEEE div, matches ref
        v = __half2float(__float2half(v));          // fp16 round-trip (RN)
        c[r] = v * (xmv[r] * wmv) + bv;
      }
      c = __builtin_amdgcn_mfma_f32_16x16x32_f16(afh[i], bfh[j], c, 0, 0, 0);
#pragma unroll
      for (int r = 0; r < 4; ++r)
        out[(size_t)(m0 + wm + i * 16 + q * 4 + r) * N + cl] = c[r];
    }
  }
}

extern "C" void kernel_launch(void* const* d_in, const int* in_sizes, int n_in,
                              void* d_out, int out_size, void* d_ws, size_t ws_size,
                              hipStream_t stream) {
  const float* x    = (const float*)d_in[0];   // 4096 x 2048
  const float* w    = (const float*)d_in[1];   // 2048 x 2048
  const float* bias = (const float*)d_in[2];   // 2048
  float* out = (float*)d_out;
  char* ws = (char*)d_ws;

  float* cm2       = (float*)(ws + 0);             // 16 x 2048 partials = 128 KB
  float* w_max     = (float*)(ws + 131072);        // 8 KB
  float* x_max     = (float*)(ws + 139264);        // 16 KB
  _Float16* x_unqh = (_Float16*)(ws + 155648);     // 256 KB
  _Float16* w_unqh = (_Float16*)(ws + 417792);     // 128 KB
  signed char* w_q = (signed char*)(ws + 548864);     // 4 MB
  signed char* x_q = (signed char*)(ws + 4743168);    // 8 MB (total ~12.5 MB)

  // no memset needed: cm2 fully written by colmax before quant reads it
  colmax_kernel<<<dim3(8, 16), 256, 0, stream>>>(w, cm2);
  quant_topk_kernel<<<512, 256, 0, stream>>>(x, w, cm2, x_q, w_q,
                                             x_max, w_max, x_unqh, w_unqh);
  gemm_kernel<<<dim3(O_DIM / 128, B_DIM / 128), 256, 0, stream>>>(
      x_q, w_q, x_max, w_max, x_unqh, w_unqh, bias, out);
}

// Round 9
// 136.833 us; speedup vs baseline: 1.8363x; 1.1152x over previous
//
#include <hip/hip_runtime.h>
#include <hip/hip_fp16.h>
#include <stdint.h>

#define I_DIM 2048
#define O_DIM 2048
#define B_DIM 4096
#define KOUT 16

typedef int i32x4 __attribute__((ext_vector_type(4)));
typedef float f32x4 __attribute__((ext_vector_type(4)));
typedef _Float16 f16x8 __attribute__((ext_vector_type(8)));

#define TO_LDS(p) ((__attribute__((address_space(3))) void*)(p))
#define TO_GLB(p) ((const __attribute__((address_space(1))) void*)(p))

// ---------------- Stage 1: column absmax of W (round-5 proven shape) ----------------
// grid (8,64): 512 blocks, 32 rows each -> pipelined cold reads, 2 blocks/CU.
__global__ void colmax_kernel(const float* __restrict__ W, unsigned* __restrict__ cm) {
  int j = blockIdx.x * 256 + threadIdx.x;       // column
  int i0 = blockIdx.y * 32;                     // row chunk
  float m0 = 0.0f, m1 = 0.0f;                   // 2 chains: expose load-level parallelism
  const float* p = W + (size_t)i0 * I_DIM + j;
#pragma unroll 8
  for (int i = 0; i < 32; i += 2) {
    m0 = fmaxf(m0, fabsf(p[(size_t)i * I_DIM]));
    m1 = fmaxf(m1, fabsf(p[(size_t)(i + 1) * I_DIM]));
  }
  atomicMax(cm + j, __float_as_uint(fmaxf(m0, m1)));  // nonneg: uint order == float order
}

// ---------------- Stage 2: per-block topk recompute + quantize 12 rows ----------------
__global__ __launch_bounds__(256) void quant_topk_kernel(
    const float* __restrict__ X, const float* __restrict__ W,
    const unsigned* __restrict__ cm,
    signed char* __restrict__ xq, signed char* __restrict__ wq,
    float* __restrict__ xmax, float* __restrict__ wmax,
    _Float16* __restrict__ xunqh,   // [B][32] halves (k padded 16->32 w/ zeros)
    _Float16* __restrict__ wunqh) { // [O][32] halves
  __shared__ float keepL[I_DIM];    // 8 KB
  __shared__ int idxL[KOUT];
  __shared__ float wm_[4];
  __shared__ int wi_[4];
  __shared__ int sel;

  const int t = threadIdx.x;

  // ---- local top-16 (identical algorithm & tie-breaks as the verified kernel) ----
  const float4* c4 = (const float4*)cm;
  float4 a = c4[t * 2], b = c4[t * 2 + 1];
  float v[8] = {a.x, a.y, a.z, a.w, b.x, b.y, b.z, b.w};
  {
    float4 one = {1.0f, 1.0f, 1.0f, 1.0f};
    ((float4*)keepL)[t] = one;
    ((float4*)keepL)[t + 256] = one;
  }
  for (int k = 0; k < KOUT; ++k) {
    float m = v[0]; int mi = 0;
#pragma unroll
    for (int r = 1; r < 8; ++r) if (v[r] > m) { m = v[r]; mi = r; }
    int gi = t * 8 + mi;
#pragma unroll
    for (int s = 32; s; s >>= 1) {
      float om = __shfl_down(m, s);
      int oi = __shfl_down(gi, s);
      if (om > m) { m = om; gi = oi; }
    }
    if ((t & 63) == 0) { wm_[t >> 6] = m; wi_[t >> 6] = gi; }
    __syncthreads();
    if (t == 0) {
      float bm = wm_[0]; int bi = wi_[0];
      for (int w2 = 1; w2 < 4; ++w2) if (wm_[w2] > bm) { bm = wm_[w2]; bi = wi_[w2]; }
      idxL[k] = bi; keepL[bi] = 0.0f; sel = bi;
    }
    __syncthreads();
    if (t == (sel >> 3)) v[sel & 7] = -1.0f;
  }
  __syncthreads();   // keepL / idxL fully visible to all waves

  // ---- quantize: one row per wave, 3 rounds (12 rows / 4 waves) ----
  const int wave = t >> 6;
  const int lane = t & 63;
  for (int rr = wave; rr < 12; rr += 4) {
    const int u = blockIdx.x * 12 + rr;           // 0..6143
    const bool isW = u < O_DIM;
    const int r = isW ? u : (u - O_DIM);
    const float* src = isW ? (W + (size_t)r * I_DIM) : (X + (size_t)r * I_DIM);
    const float4* s4 = (const float4*)src;
    const float4* k4 = (const float4*)keepL;

    float4 d[8];
    float mx = 0.0f;
#pragma unroll
    for (int i = 0; i < 8; ++i) {                 // coalesced: float4 index i*64+lane
      float4 dv = s4[i * 64 + lane];
      float4 kk = k4[i * 64 + lane];
      dv.x *= kk.x; dv.y *= kk.y; dv.z *= kk.z; dv.w *= kk.w;
      d[i] = dv;
      mx = fmaxf(mx, fmaxf(fmaxf(fabsf(dv.x), fabsf(dv.y)),
                           fmaxf(fabsf(dv.z), fabsf(dv.w))));
    }
#pragma unroll
    for (int s = 32; s; s >>= 1) mx = fmaxf(mx, __shfl_xor(mx, s));
    const float sc = 127.0f / mx;                 // match ref: scale first, mul, trunc
    unsigned* qout = (unsigned*)(isW ? (wq + (size_t)r * I_DIM) : (xq + (size_t)r * I_DIM));
#pragma unroll
    for (int i = 0; i < 8; ++i) {
      unsigned p = (unsigned char)(signed char)(int)(d[i].x * sc)
                 | ((unsigned)(unsigned char)(signed char)(int)(d[i].y * sc) << 8)
                 | ((unsigned)(unsigned char)(signed char)(int)(d[i].z * sc) << 16)
                 | ((unsigned)(unsigned char)(signed char)(int)(d[i].w * sc) << 24);
      __builtin_nontemporal_store(p, &qout[i * 64 + lane]);   // bypass L2: no dirty flush
    }
    if (lane == 0) { if (isW) wmax[r] = mx; else xmax[r] = mx; }
    if (lane < KOUT) {
      float ov = src[idxL[lane]];
      _Float16* u16 = isW ? (wunqh + (size_t)r * 32) : (xunqh + (size_t)r * 32);
      u16[lane] = (_Float16)ov;
      u16[lane + KOUT] = (_Float16)0.0f;          // zero-pad k 16..31
    }
  }
}

// ---------------- Stage 3: int8 GEMM (C = Xq * Wq^T) + fused MFMA epilogue ----------------
// Round-5 verified structure: BK=128, double-buffered LDS, prefetch-before-compute,
// one __syncthreads per chunk, XCD-aware block swizzle. NT stores on out.
__global__ __launch_bounds__(256, 2) void gemm_kernel(
    const signed char* __restrict__ Aq,   // M x K (x_q)
    const signed char* __restrict__ Bq,   // N x K (w_q)
    const float* __restrict__ xmaxg,      // M
    const float* __restrict__ wmaxg,      // N
    const _Float16* __restrict__ xunqh,   // M x 32
    const _Float16* __restrict__ wunqh,   // N x 32
    const float* __restrict__ biasg,      // N
    float* __restrict__ out) {            // M x N
  constexpr int N = O_DIM, K = I_DIM;
  __shared__ __align__(16) signed char smem[2][32768];  // per buf: As 16K | Bs 16K

  const int tid = threadIdx.x;
  const int lane = tid & 63;
  const int wave = tid >> 6;
  const int wm = (wave & 1) * 64;
  const int wn = (wave >> 1) * 64;

  // XCD swizzle: 64 tiles per XCD, 8x8 regions
  const int lid = blockIdx.y * gridDim.x + blockIdx.x;   // 0..511
  const int xcd = lid & 7;
  const int pos = lid >> 3;                              // 0..63
  const int by = (xcd >> 1) * 8 + (pos >> 3);            // 0..31 (M tiles)
  const int bx = (xcd & 1) * 8 + (pos & 7);              // 0..15 (N tiles)
  const int m0 = by * 128;
  const int n0 = bx * 128;

  const int srow = tid >> 3;              // 0..31
  const int cslot = tid & 7;              // 0..7
  const int fm = lane & 15;
  const int q = lane >> 4;

  i32x4 acc[4][4] = {};

  // chunk swizzle: LDS slot (r, c) holds global 16B-chunk (c - (r>>1)) & 7
  auto stage = [&](int buf, int kt) {
    signed char* As = &smem[buf][0];
    signed char* Bs = &smem[buf][16384];
#pragma unroll
    for (int a = 0; a < 4; ++a) {
      const int row = a * 32 + srow;
      const int gch = (cslot - (row >> 1)) & 7;
      const signed char* ga = Aq + (size_t)(m0 + row) * K + kt + gch * 16;
      const signed char* gb = Bq + (size_t)(n0 + row) * K + kt + gch * 16;
      __builtin_amdgcn_global_load_lds(TO_GLB(ga), TO_LDS(As + a * 4096 + tid * 16), 16, 0, 0);
      __builtin_amdgcn_global_load_lds(TO_GLB(gb), TO_LDS(Bs + a * 4096 + tid * 16), 16, 0, 0);
    }
  };

  stage(0, 0);
  __syncthreads();
#pragma unroll 2
  for (int t = 0; t < K / 128; ++t) {             // 16 iterations
    const int cur = t & 1;
    if (t < K / 128 - 1) stage(cur ^ 1, (t + 1) * 128);   // prefetch first
    const signed char* As = &smem[cur][0];
    const signed char* Bs = &smem[cur][16384];
#pragma unroll
    for (int s = 0; s < 2; ++s) {
      i32x4 af[4], bf[4];
      const int q8 = s * 4 + q;
#pragma unroll
      for (int i = 0; i < 4; ++i) {
        const int ra = wm + i * 16 + fm;
        af[i] = *(const i32x4*)(As + ra * 128 + (((q8 + (ra >> 1)) & 7) << 4));
        const int rb = wn + i * 16 + fm;
        bf[i] = *(const i32x4*)(Bs + rb * 128 + (((q8 + (rb >> 1)) & 7) << 4));
      }
#pragma unroll
      for (int i = 0; i < 4; ++i)
#pragma unroll
        for (int j = 0; j < 4; ++j)
          acc[i][j] = __builtin_amdgcn_mfma_i32_16x16x64_i8(af[i], bf[j], acc[i][j], 0, 0, 0);
    }
    __syncthreads();
  }

  // ---- epilogue: dequant + fp16 round-trip + rank-16 outlier MFMA + bias ----
  f16x8 afh[4], bfh[4];
#pragma unroll
  for (int i = 0; i < 4; ++i)
    afh[i] = *(const f16x8*)(xunqh + (size_t)(m0 + wm + i * 16 + fm) * 32 + q * 8);
#pragma unroll
  for (int j = 0; j < 4; ++j)
    bfh[j] = *(const f16x8*)(wunqh + (size_t)(n0 + wn + j * 16 + fm) * 32 + q * 8);

#pragma unroll
  for (int i = 0; i < 4; ++i) {
    f32x4 xmv = *(const f32x4*)(xmaxg + m0 + wm + i * 16 + q * 4);
#pragma unroll
    for (int j = 0; j < 4; ++j) {
      int cl = n0 + wn + j * 16 + fm;
      float wmv = wmaxg[cl];
      float bv = biasg[cl];
      f32x4 c;
#pragma unroll
      for (int r = 0; r < 4; ++r) {
        float v = (float)acc[i][j][r] / 16129.0f;   // IEEE div, matches ref
        v = __half2float(__float2half(v));          // fp16 round-trip (RN)
        c[r] = v * (xmv[r] * wmv) + bv;
      }
      c = __builtin_amdgcn_mfma_f32_16x16x32_f16(afh[i], bfh[j], c, 0, 0, 0);
#pragma unroll
      for (int r = 0; r < 4; ++r)
        __builtin_nontemporal_store(c[r],
            &out[(size_t)(m0 + wm + i * 16 + q * 4 + r) * N + cl]);  // bypass L2
    }
  }
}

extern "C" void kernel_launch(void* const* d_in, const int* in_sizes, int n_in,
                              void* d_out, int out_size, void* d_ws, size_t ws_size,
                              hipStream_t stream) {
  const float* x    = (const float*)d_in[0];   // 4096 x 2048
  const float* w    = (const float*)d_in[1];   // 2048 x 2048
  const float* bias = (const float*)d_in[2];   // 2048
  float* out = (float*)d_out;
  char* ws = (char*)d_ws;

  unsigned* cm     = (unsigned*)(ws + 0);          // 8 KB
  float* w_max     = (float*)(ws + 8192);          // 8 KB
  float* x_max     = (float*)(ws + 16384);         // 16 KB
  _Float16* x_unqh = (_Float16*)(ws + 32768);      // 256 KB
  _Float16* w_unqh = (_Float16*)(ws + 294912);     // 128 KB
  signed char* w_q = (signed char*)(ws + 425984);     // 4 MB
  signed char* x_q = (signed char*)(ws + 4620288);    // 8 MB (total ~12.4 MB)

  hipMemsetAsync(cm, 0, 8192, stream);
  colmax_kernel<<<dim3(8, 64), 256, 0, stream>>>(w, cm);
  quant_topk_kernel<<<512, 256, 0, stream>>>(x, w, cm, x_q, w_q,
                                             x_max, w_max, x_unqh, w_unqh);
  gemm_kernel<<<dim3(O_DIM / 128, B_DIM / 128), 256, 0, stream>>>(
      x_q, w_q, x_max, w_max, x_unqh, w_unqh, bias, out);
}